// Round 2
// baseline (217.148 us; speedup 1.0000x reference)
//
#include <hip/hip_runtime.h>
#include <hip/hip_bf16.h>

typedef __attribute__((ext_vector_type(4))) float  f4;
typedef __attribute__((ext_vector_type(4))) float  f32x4;
typedef __attribute__((ext_vector_type(8))) short  bf8;

__device__ __forceinline__ short f2bf(float f) {
    unsigned u = __builtin_bit_cast(unsigned, f);
    u += 0x7fff + ((u >> 16) & 1);          // round-to-nearest-even
    return (short)(u >> 16);
}

// ---------------------------------------------------------------------------
// Prep: build the fused B-matrix [256][128] (k-major) and pack it into
// per-lane MFMA fragment order for mfma_f32_16x16x32_bf16.
//   Bmat[k][n] = k<128 ? U_w[n][k]
//                      : A_w[n][k-128]*dw[k-128]/dw[n] + (n==k-128)*(0.05-rs[n])
// Fragment order: pre[((t*8+nt)*64 + lane)*8 + j] = Bmat[t*32+(lane>>4)*8+j][nt*16+(lane&15)]
// ---------------------------------------------------------------------------
__global__ void nemon_prep(const float* __restrict__ Uw,
                           const float* __restrict__ Aw,
                           const float* __restrict__ dvec,
                           short* __restrict__ pre)
{
    __shared__ float rs[128], dwv[128];
    const int tid = threadIdx.x;
    if (tid < 128) {
        float s = 0.f;
        #pragma unroll 8
        for (int k = 0; k < 128; ++k) s += fabsf(Aw[tid * 128 + k]);
        rs[tid]  = s;
        dwv[tid] = expf(dvec[tid]);
    }
    __syncthreads();
    for (int e = tid; e < 32768; e += 256) {
        const int j    = e & 7;
        const int lane = (e >> 3) & 63;
        const int tnt  = e >> 9;          // 0..63
        const int nt   = tnt & 7;
        const int t    = tnt >> 3;        // k-tile 0..7
        const int k    = t * 32 + (lane >> 4) * 8 + j;
        const int n    = nt * 16 + (lane & 15);
        float v;
        if (k < 128) {
            v = Uw[n * 128 + k];
        } else {
            const int k2 = k - 128;
            v = Aw[n * 128 + k2] * (dwv[k2] / dwv[n]);
            if (n == k2) v += 0.05f - rs[n];
        }
        pre[e] = f2bf(v);
    }
}

// ---------------------------------------------------------------------------
// Main: streaming GEMM. Each block: 4 waves, 64 batch rows per tile,
// grid-stride over tiles. W (64 KB) staged in LDS once per block.
// ---------------------------------------------------------------------------
__global__ __launch_bounds__(256, 2) void nemon_main(
    const float* __restrict__ x,
    const float* __restrict__ z,
    const float* __restrict__ Ub,
    const short* __restrict__ pre,
    float* __restrict__ out,
    int ntiles)
{
    __shared__ short W[32768];            // 64 KB fragment-packed weights
    const int tid = threadIdx.x;

    {   // stage prepacked weights (linear, coalesced)
        const int4* src = (const int4*)pre;
        int4*       dst = (int4*)W;
        #pragma unroll
        for (int i = 0; i < 16; ++i) dst[tid + 256 * i] = src[tid + 256 * i];
    }
    __syncthreads();

    const int wave = tid >> 6;
    const int lane = tid & 63;
    const int mrow = lane & 15;           // A-row within tile / C-col
    const int kgrp = lane >> 4;           // 0..3

    float ub[8];
    #pragma unroll
    for (int nt = 0; nt < 8; ++nt) ub[nt] = Ub[nt * 16 + mrow];

    for (int tile = blockIdx.x; tile < ntiles; tile += gridDim.x) {
        const long row = (long)tile * 64 + wave * 16 + mrow;
        const f4* xv = (const f4*)(x + row * 128 + kgrp * 8);
        const f4* zv = (const f4*)(z + row * 128 + kgrp * 8);

        f4 xa[4][2], za[4][2];
        #pragma unroll
        for (int kt = 0; kt < 4; ++kt) {
            xa[kt][0] = xv[kt * 8];
            xa[kt][1] = xv[kt * 8 + 1];
            za[kt][0] = zv[kt * 8];
            za[kt][1] = zv[kt * 8 + 1];
        }

        bf8 ax[4], az[4];
        #pragma unroll
        for (int kt = 0; kt < 4; ++kt) {
            #pragma unroll
            for (int q = 0; q < 4; ++q) {
                ax[kt][q]     = f2bf(xa[kt][0][q]);
                ax[kt][4 + q] = f2bf(xa[kt][1][q]);
                az[kt][q]     = f2bf(za[kt][0][q]);
                az[kt][4 + q] = f2bf(za[kt][1][q]);
            }
        }

        f32x4 acc[8];
        #pragma unroll
        for (int nt = 0; nt < 8; ++nt)
            acc[nt] = (f32x4){ub[nt], ub[nt], ub[nt], ub[nt]};

        #pragma unroll
        for (int kt = 0; kt < 4; ++kt) {
            #pragma unroll
            for (int nt = 0; nt < 8; ++nt) {
                bf8 b = *(const bf8*)&W[(kt * 8 + nt) * 512 + lane * 8];
                acc[nt] = __builtin_amdgcn_mfma_f32_16x16x32_bf16(ax[kt], b, acc[nt], 0, 0, 0);
            }
        }
        #pragma unroll
        for (int kt = 0; kt < 4; ++kt) {
            #pragma unroll
            for (int nt = 0; nt < 8; ++nt) {
                bf8 b = *(const bf8*)&W[((4 + kt) * 8 + nt) * 512 + lane * 8];
                acc[nt] = __builtin_amdgcn_mfma_f32_16x16x32_bf16(az[kt], b, acc[nt], 0, 0, 0);
            }
        }

        // C layout (m89): col = lane&15, row = (lane>>4)*4 + j
        float* obase = out + ((long)tile * 64 + wave * 16 + kgrp * 4) * 128 + mrow;
        #pragma unroll
        for (int nt = 0; nt < 8; ++nt) {
            #pragma unroll
            for (int j = 0; j < 4; ++j)
                obase[j * 128 + nt * 16] = acc[nt][j];
        }
    }
}

extern "C" void kernel_launch(void* const* d_in, const int* in_sizes, int n_in,
                              void* d_out, int out_size, void* d_ws, size_t ws_size,
                              hipStream_t stream) {
    const float* x  = (const float*)d_in[0];
    const float* z  = (const float*)d_in[1];
    const float* Uw = (const float*)d_in[2];
    const float* Ub = (const float*)d_in[3];
    const float* Aw = (const float*)d_in[4];
    const float* dv = (const float*)d_in[5];
    float* out = (float*)d_out;
    short* pre = (short*)d_ws;            // 64 KB prepacked weights

    const int B      = in_sizes[0] / 128;
    const int ntiles = B / 64;

    nemon_prep<<<1, 256, 0, stream>>>(Uw, Aw, dv, pre);
    nemon_main<<<1024, 256, 0, stream>>>(x, z, Ub, pre, out, ntiles);
}

// Round 3
// 120.317 us; speedup vs baseline: 1.8048x; 1.8048x over previous
//
#include <hip/hip_runtime.h>
#include <hip/hip_bf16.h>

typedef __attribute__((ext_vector_type(4))) float  f4;
typedef __attribute__((ext_vector_type(4))) float  f32x4;
typedef __attribute__((ext_vector_type(8))) short  bf8;
typedef __attribute__((ext_vector_type(4))) short  s4;

__device__ __forceinline__ short f2bf(float f) {
    unsigned u = __builtin_bit_cast(unsigned, f);
    u += 0x7fff + ((u >> 16) & 1);          // round-to-nearest-even
    return (short)(u >> 16);
}

// ---------------------------------------------------------------------------
// Prep (unchanged, verified): fused B-matrix [256][128] packed in MFMA
// B-fragment order for mfma_f32_16x16x32_bf16.
//   Bmat[k][n] = k<128 ? U_w[n][k]
//                      : A_w[n][k-128]*dw[k-128]/dw[n] + (n==k-128)*(0.05-rs[n])
//   pre[((kt*8+nt)*64 + lane)*8 + j] = Bmat[kt*32+(lane>>4)*8+j][nt*16+(lane&15)]
// ---------------------------------------------------------------------------
__global__ void nemon_prep(const float* __restrict__ Uw,
                           const float* __restrict__ Aw,
                           const float* __restrict__ dvec,
                           short* __restrict__ pre)
{
    __shared__ float rs[128], dwv[128];
    const int tid = threadIdx.x;
    if (tid < 128) {
        float s = 0.f;
        #pragma unroll 8
        for (int k = 0; k < 128; ++k) s += fabsf(Aw[tid * 128 + k]);
        rs[tid]  = s;
        dwv[tid] = expf(dvec[tid]);
    }
    __syncthreads();
    for (int e = tid; e < 32768; e += 256) {
        const int j    = e & 7;
        const int lane = (e >> 3) & 63;
        const int tnt  = e >> 9;
        const int nt   = tnt & 7;
        const int t    = tnt >> 3;
        const int k    = t * 32 + (lane >> 4) * 8 + j;
        const int n    = nt * 16 + (lane & 15);
        float v;
        if (k < 128) {
            v = Uw[n * 128 + k];
        } else {
            const int k2 = k - 128;
            v = Aw[n * 128 + k2] * (dwv[k2] / dwv[n]);
            if (n == k2) v += 0.05f - rs[n];
        }
        pre[e] = f2bf(v);
    }
}

// ---------------------------------------------------------------------------
// Main v4: 32-row tiles, 256 threads (4 waves). Weights in REGISTERS
// (each wave owns nt-pair {2w, 2w+1}: 16 frags = 64 VGPRs). LDS = 16 KB
// staging only -> 3 blocks/CU. All global access fully coalesced 16 B/lane;
// input transposed to fragment layout via XOR-swizzled LDS; output
// transposed back via LDS epilogue -> dwordx4 stores.
// ---------------------------------------------------------------------------
__global__ __launch_bounds__(256, 3) void nemon_main(
    const float* __restrict__ x,
    const float* __restrict__ z,
    const float* __restrict__ Ub,
    const short* __restrict__ pre,
    float* __restrict__ out,
    int ntiles)
{
    __shared__ char S[16384];             // bf16 [32 rows][256 k] / f32 [32][128]
    const int tid  = threadIdx.x;
    const int wave = tid >> 6;
    const int lane = tid & 63;
    const int mrow = lane & 15;           // MFMA n-index (C col) and A row
    const int kgrp = lane >> 4;           // 0..3

    // --- hoist this wave's weight fragments to registers (nt = 2*wave + j)
    bf8 wreg[8][2];
    #pragma unroll
    for (int kt = 0; kt < 8; ++kt) {
        #pragma unroll
        for (int j = 0; j < 2; ++j)
            wreg[kt][j] = *(const bf8*)&pre[((kt * 8 + (2 * wave + j)) * 64 + lane) * 8];
    }
    const float ub0 = Ub[(2 * wave)     * 16 + mrow];
    const float ub1 = Ub[(2 * wave + 1) * 16 + mrow];

    for (int tile = blockIdx.x; tile < ntiles; tile += gridDim.x) {
        const long base = (long)tile * 4096;     // 32 rows * 128 floats

        // --- coalesced tile loads (issued before barrier for overlap)
        f4 xv[4], zv[4];
        #pragma unroll
        for (int i = 0; i < 4; ++i) xv[i] = *(const f4*)(x + base + (tid + i * 256) * 4);
        #pragma unroll
        for (int i = 0; i < 4; ++i) zv[i] = *(const f4*)(z + base + (tid + i * 256) * 4);

        __syncthreads();   // prior iteration's epilogue reads of S are done

        // --- convert to bf16, swizzled LDS write (8 B granules)
        #pragma unroll
        for (int i = 0; i < 4; ++i) {
            const int c   = tid + i * 256;       // 16B-chunk id, 32 per row
            const int row = c >> 5;
            const int k2  = (c & 31) * 8;        // byte offset of 4 bf16
            const int swz = (row & 7) << 4;
            s4 px = { f2bf(xv[i][0]), f2bf(xv[i][1]), f2bf(xv[i][2]), f2bf(xv[i][3]) };
            s4 pz = { f2bf(zv[i][0]), f2bf(zv[i][1]), f2bf(zv[i][2]), f2bf(zv[i][3]) };
            *(s4*)(S + row * 512 + ( k2         ^ swz)) = px;
            *(s4*)(S + row * 512 + ((k2 + 256)  ^ swz)) = pz;   // z at k=128..255
        }
        __syncthreads();

        // --- MFMA: A-frags from swizzled LDS, B-frags from registers
        f32x4 acc[2][2];
        acc[0][0] = (f32x4){ub0, ub0, ub0, ub0};
        acc[1][0] = acc[0][0];
        acc[0][1] = (f32x4){ub1, ub1, ub1, ub1};
        acc[1][1] = acc[0][1];
        #pragma unroll
        for (int m2 = 0; m2 < 2; ++m2) {
            const int row   = m2 * 16 + mrow;
            const int rbase = row * 512;
            const int swz   = (row & 7) << 4;
            #pragma unroll
            for (int kt = 0; kt < 8; ++kt) {
                bf8 a = *(const bf8*)(S + rbase + ((kt * 64 + kgrp * 16) ^ swz));
                acc[m2][0] = __builtin_amdgcn_mfma_f32_16x16x32_bf16(a, wreg[kt][0], acc[m2][0], 0, 0, 0);
                acc[m2][1] = __builtin_amdgcn_mfma_f32_16x16x32_bf16(a, wreg[kt][1], acc[m2][1], 0, 0, 0);
            }
        }
        __syncthreads();   // all frag reads done; S reusable as f32 epilogue buf

        // --- epilogue: C-frags -> LDS f32 [32 rows][128 cols]
        float* SF = (float*)S;
        #pragma unroll
        for (int m2 = 0; m2 < 2; ++m2) {
            #pragma unroll
            for (int j2 = 0; j2 < 2; ++j2) {
                #pragma unroll
                for (int jj = 0; jj < 4; ++jj)
                    SF[(m2 * 16 + kgrp * 4 + jj) * 128 + (2 * wave + j2) * 16 + mrow] = acc[m2][j2][jj];
            }
        }
        __syncthreads();

        // --- coalesced dwordx4 stores
        #pragma unroll
        for (int i = 0; i < 4; ++i) {
            f4 v = *(const f4*)(S + (tid + i * 256) * 16);
            *(f4*)(out + base + (tid + i * 256) * 4) = v;
        }
    }
}

extern "C" void kernel_launch(void* const* d_in, const int* in_sizes, int n_in,
                              void* d_out, int out_size, void* d_ws, size_t ws_size,
                              hipStream_t stream) {
    const float* x  = (const float*)d_in[0];
    const float* z  = (const float*)d_in[1];
    const float* Uw = (const float*)d_in[2];
    const float* Ub = (const float*)d_in[3];
    const float* Aw = (const float*)d_in[4];
    const float* dv = (const float*)d_in[5];
    float* out = (float*)d_out;
    short* pre = (short*)d_ws;            // 64 KB prepacked weights

    const int B      = in_sizes[0] / 128;
    const int ntiles = B / 32;            // 32-row tiles

    nemon_prep<<<1, 256, 0, stream>>>(Uw, Aw, dv, pre);
    nemon_main<<<2048, 256, 0, stream>>>(x, z, Ub, pre, out, ntiles);
}

// Round 5
// 120.065 us; speedup vs baseline: 1.8086x; 1.0021x over previous
//
#include <hip/hip_runtime.h>
#include <hip/hip_bf16.h>

typedef __attribute__((ext_vector_type(4))) float  f4;
typedef __attribute__((ext_vector_type(4))) float  f32x4;
typedef __attribute__((ext_vector_type(8))) short  bf8;
typedef __attribute__((ext_vector_type(4))) short  s4;

__device__ __forceinline__ short f2bf(float f) {
    unsigned u = __builtin_bit_cast(unsigned, f);
    u += 0x7fff + ((u >> 16) & 1);          // round-to-nearest-even
    return (short)(u >> 16);
}

// ---------------------------------------------------------------------------
// Prep (unchanged, verified): fused B-matrix [256][128] packed in MFMA
// B-fragment order for mfma_f32_16x16x32_bf16.
//   Bmat[k][n] = k<128 ? U_w[n][k]
//                      : A_w[n][k-128]*dw[k-128]/dw[n] + (n==k-128)*(0.05-rs[n])
//   pre[((kt*8+nt)*64 + lane)*8 + j] = Bmat[kt*32+(lane>>4)*8+j][nt*16+(lane&15)]
// ---------------------------------------------------------------------------
__global__ void nemon_prep(const float* __restrict__ Uw,
                           const float* __restrict__ Aw,
                           const float* __restrict__ dvec,
                           short* __restrict__ pre)
{
    __shared__ float rs[128], dwv[128];
    const int tid = threadIdx.x;
    if (tid < 128) {
        float s = 0.f;
        #pragma unroll 8
        for (int k = 0; k < 128; ++k) s += fabsf(Aw[tid * 128 + k]);
        rs[tid]  = s;
        dwv[tid] = expf(dvec[tid]);
    }
    __syncthreads();
    for (int e = tid; e < 32768; e += 256) {
        const int j    = e & 7;
        const int lane = (e >> 3) & 63;
        const int tnt  = e >> 9;
        const int nt   = tnt & 7;
        const int t    = tnt >> 3;
        const int k    = t * 32 + (lane >> 4) * 8 + j;
        const int n    = nt * 16 + (lane & 15);
        float v;
        if (k < 128) {
            v = Uw[n * 128 + k];
        } else {
            const int k2 = k - 128;
            v = Aw[n * 128 + k2] * (dwv[k2] / dwv[n]);
            if (n == k2) v += 0.05f - rs[n];
        }
        pre[e] = f2bf(v);
    }
}

// ---------------------------------------------------------------------------
// Main v5: software-pipelined. Per iter: convert(i) | bar | prefetch(i+1) +
// MFMA(i) + epilogue(i) | bar | store(i). Loads for i+1 in flight across
// the whole compute+store phase. LDS: in0|in1 (16 KB bf16 staging, double-
// buffered) + out (16 KB f32 epilogue) = 48 KB -> 3 blocks/CU.
// Epilogue bank-conflict fixed by XOR swizzle (2 lanes/bank = free).
// ---------------------------------------------------------------------------
__global__ __launch_bounds__(256, 3) void nemon_main(
    const float* __restrict__ x,
    const float* __restrict__ z,
    const float* __restrict__ Ub,
    const short* __restrict__ pre,
    float* __restrict__ out,
    int ntiles)
{
    __shared__ char S[49152];
    float* OF = (float*)(S + 32768);      // f32 epilogue buffer [32][128]

    const int tid  = threadIdx.x;
    const int wave = tid >> 6;
    const int lane = tid & 63;
    const int mrow = lane & 15;           // MFMA A-row / C-col
    const int kgrp = lane >> 4;           // 0..3

    // --- prologue global loads for tile 0 (issued first: HBM-cold)
    const int niter = (ntiles > (int)blockIdx.x)
                    ? (ntiles - blockIdx.x + gridDim.x - 1) / gridDim.x : 0;
    long base = (long)blockIdx.x * 4096;
    const long bstride = (long)gridDim.x * 4096;

    f4 xv[4], zv[4];
    if (niter > 0) {
        #pragma unroll
        for (int i = 0; i < 4; ++i) xv[i] = *(const f4*)(x + base + (tid + i * 256) * 4);
        #pragma unroll
        for (int i = 0; i < 4; ++i) zv[i] = *(const f4*)(z + base + (tid + i * 256) * 4);
    }

    // --- hoist this wave's weight fragments to registers (L2-hot)
    bf8 wreg[8][2];
    #pragma unroll
    for (int kt = 0; kt < 8; ++kt) {
        #pragma unroll
        for (int j = 0; j < 2; ++j)
            wreg[kt][j] = *(const bf8*)&pre[((kt * 8 + (2 * wave + j)) * 64 + lane) * 8];
    }
    const float ub0 = Ub[(2 * wave)     * 16 + mrow];
    const float ub1 = Ub[(2 * wave + 1) * 16 + mrow];

    for (int it = 0; it < niter; ++it) {
        char* inb = S + ((it & 1) << 14);
        const long cur = base;

        // --- A: convert regs -> bf16, swizzled LDS write
        #pragma unroll
        for (int i = 0; i < 4; ++i) {
            const int c   = tid + i * 256;       // 16B-chunk id, 32 per row
            const int row = c >> 5;
            const int k2  = (c & 31) * 8;
            const int swz = (row & 7) << 4;
            s4 px = { f2bf(xv[i][0]), f2bf(xv[i][1]), f2bf(xv[i][2]), f2bf(xv[i][3]) };
            s4 pz = { f2bf(zv[i][0]), f2bf(zv[i][1]), f2bf(zv[i][2]), f2bf(zv[i][3]) };
            *(s4*)(inb + row * 512 + ( k2        ^ swz)) = px;
            *(s4*)(inb + row * 512 + ((k2 + 256) ^ swz)) = pz;
        }
        __syncthreads();   // inb visible; prev store reads of OF done; prev MFMA reads of inb done

        // --- C: prefetch next tile (in flight across MFMA+epilogue+store)
        base += bstride;
        if (it + 1 < niter) {
            #pragma unroll
            for (int i = 0; i < 4; ++i) xv[i] = *(const f4*)(x + base + (tid + i * 256) * 4);
            #pragma unroll
            for (int i = 0; i < 4; ++i) zv[i] = *(const f4*)(z + base + (tid + i * 256) * 4);
        }

        // --- D: MFMA (A from swizzled LDS, B from registers)
        f32x4 acc[2][2];
        acc[0][0] = (f32x4){ub0, ub0, ub0, ub0};
        acc[1][0] = acc[0][0];
        acc[0][1] = (f32x4){ub1, ub1, ub1, ub1};
        acc[1][1] = acc[0][1];
        #pragma unroll
        for (int m2 = 0; m2 < 2; ++m2) {
            const int rbase = (m2 * 16 + mrow) * 512;
            const int swz   = (mrow & 7) << 4;     // (row&7)==(mrow&7)
            #pragma unroll
            for (int kt = 0; kt < 8; ++kt) {
                bf8 a = *(const bf8*)(inb + rbase + ((kt * 64 + kgrp * 16) ^ swz));
                acc[m2][0] = __builtin_amdgcn_mfma_f32_16x16x32_bf16(a, wreg[kt][0], acc[m2][0], 0, 0, 0);
                acc[m2][1] = __builtin_amdgcn_mfma_f32_16x16x32_bf16(a, wreg[kt][1], acc[m2][1], 0, 0, 0);
            }
        }

        // --- E: epilogue C-frags -> OF with bank swizzle
        //     dword idx = row*128 + (col ^ (kgrp<<2) ^ ((kgrp>>1)<<4)); kgrp=(row>>2)&3
        #pragma unroll
        for (int m2 = 0; m2 < 2; ++m2) {
            #pragma unroll
            for (int j2 = 0; j2 < 2; ++j2) {
                const int col  = (2 * wave + j2) * 16 + mrow;
                const int cols = col ^ (kgrp << 2) ^ ((kgrp >> 1) << 4);
                #pragma unroll
                for (int jj = 0; jj < 4; ++jj)
                    OF[(m2 * 16 + kgrp * 4 + jj) * 128 + cols] = acc[m2][j2][jj];
            }
        }
        __syncthreads();   // OF complete; inb MFMA reads done

        // --- G: coalesced swizzle-inverting dwordx4 stores
        #pragma unroll
        for (int i = 0; i < 4; ++i) {
            const int q = tid + i * 256;          // f4-slot id, 32 per row
            const int r = q >> 5;
            const int c = q & 31;
            const int s = (r >> 2) & 3;
            f4 v = *(const f4*)((char*)OF + r * 512 + (((c << 4) ^ (s << 4) ^ ((s >> 1) << 6))));
            *(f4*)(out + cur + q * 4) = v;
        }
    }
}

extern "C" void kernel_launch(void* const* d_in, const int* in_sizes, int n_in,
                              void* d_out, int out_size, void* d_ws, size_t ws_size,
                              hipStream_t stream) {
    const float* x  = (const float*)d_in[0];
    const float* z  = (const float*)d_in[1];
    const float* Uw = (const float*)d_in[2];
    const float* Ub = (const float*)d_in[3];
    const float* Aw = (const float*)d_in[4];
    const float* dv = (const float*)d_in[5];
    float* out = (float*)d_out;
    short* pre = (short*)d_ws;            // 64 KB prepacked weights

    const int B      = in_sizes[0] / 128;
    const int ntiles = B / 32;            // 32-row tiles

    nemon_prep<<<1, 256, 0, stream>>>(Uw, Aw, dv, pre);
    nemon_main<<<2048, 256, 0, stream>>>(x, z, Ub, pre, out, ntiles);
}